// Round 9
// baseline (157.131 us; speedup 1.0000x reference)
//
#include <hip/hip_runtime.h>
#include <hip/hip_bf16.h>

#define NB 4
#define NH 12
#define SEQ 4096
#define DIM 64
#define LOG2E 1.4426950408889634f

typedef __attribute__((ext_vector_type(8))) short short8;
typedef __attribute__((ext_vector_type(4))) float f32x4;
typedef __attribute__((ext_vector_type(2))) unsigned int u32x2;

static __device__ __forceinline__ unsigned int pk2(float a, float b) {
    float2 t; t.x = a; t.y = b;
    union { __hip_bfloat162 h; unsigned int u; } x;
    x.h = __float22bfloat162_rn(t);
    return x.u;
}
static __device__ __forceinline__ short8 mk8(unsigned int a, unsigned int b,
                                             unsigned int c, unsigned int d) {
    union { unsigned int u[4]; short8 s; } x;
    x.u[0] = a; x.u[1] = b; x.u[2] = c; x.u[3] = d;
    return x.s;
}

__global__ __launch_bounds__(1024, 4)
void blk_attn(const float* __restrict__ Q, const float* __restrict__ K,
              const float* __restrict__ V, const float* __restrict__ M,
              float* __restrict__ O) {
    int bid = blockIdx.x;
    bid = (bid & 7) * 96 + (bid >> 3);        // XCD-aware bijective swizzle (768 % 8 == 0)

    const int p  = bid & 15;                  // 256-query pair-group (j = 2p, 2p+1)
    const int bh = bid >> 4;
    const int b  = bh / NH;

    const size_t base = (size_t)bh * SEQ * DIM;
    const float* Kp = K + base;
    const float* Vp = V + base;

    const int tid  = threadIdx.x;
    const int w    = tid >> 6;      // wave 0..15
    const int lane = tid & 63;
    const int lo   = lane & 15;
    const int hi   = lane >> 4;

    // block stages 512-key union [LB, LB+512); wave's 384-key span at offset off
    const int LB  = (p == 0) ? 0 : 256 * p - 128;
    const int jj  = 2 * p + (w >> 3);          // this wave's 128-query group
    const int q0  = 256 * p + 16 * w;          // this wave's first query row
    const int kb0 = (jj == 0) ? 0 : ((jj == 31) ? SEQ - 384 : 128 * jj - 128);
    const int off = kb0 - LB;                  // 0 or 128
    const bool md = (jj != 0) && (jj != 31);
    const float wt0 = (jj == 31) ? 0.f : (md ? 0.5f : 1.f);
    const float wt1 = (jj == 0)  ? 0.f : (md ? 0.5f : 1.f);

    // ---- LDS: exactly 160 KB ----
    __shared__ __align__(16) unsigned char smem[163840];
    auto Ks = (unsigned short (*)[64])(smem);             // [512][64]: K[key][d ^ 8*(key&7)]
    auto Vt = (unsigned short (*)[512])(smem + 65536);    // [64][512]: V^T[d][k ^ 8*((d^(d>>2))&7)]
    auto Pw = (unsigned int (*)[16][32])(smem + 131072);  // [16 waves][16 q][32 dw]

    // ---- Q fragments, scaled by log2e/8 ----
    short8 qa[2];
    {
        const float qs = 0.125f * LOG2E;
        const float* qr = Q + base + (size_t)(q0 + lo) * DIM + hi * 8;
        #pragma unroll
        for (int s = 0; s < 2; ++s) {
            f32x4 a = *reinterpret_cast<const f32x4*>(qr + 32 * s);
            f32x4 c = *reinterpret_cast<const f32x4*>(qr + 32 * s + 4);
            qa[s] = mk8(pk2(a[0] * qs, a[1] * qs), pk2(a[2] * qs, a[3] * qs),
                        pk2(c[0] * qs, c[1] * qs), pk2(c[2] * qs, c[3] * qs));
        }
    }

    // ---- stage K: 512 rows once (clamped at p=15 tail; tail unused) ----
    {
        const int c8 = lane & 7, r8 = lane >> 3;
        #pragma unroll
        for (int it = 0; it < 4; ++it) {
            const int row = 8 * w + r8 + 128 * it;      // row & 7 == r8
            int krow = LB + row; krow = krow < SEQ ? krow : SEQ - 1;
            const float* kp = Kp + (size_t)krow * DIM + 8 * c8;
            f32x4 a = *reinterpret_cast<const f32x4*>(kp);
            f32x4 c = *reinterpret_cast<const f32x4*>(kp + 4);
            *reinterpret_cast<short8*>(&Ks[row][(8 * c8) ^ (8 * r8)]) =
                mk8(pk2(a[0], a[1]), pk2(a[2], a[3]), pk2(c[0], c[1]), pk2(c[2], c[3]));
        }
    }
    // ---- stage V^T: 4x4 register transpose ----
    {
        const int quad = lane & 3, colq = lane >> 2;
        #pragma unroll
        for (int it = 0; it < 2; ++it) {
            const int kg = w + 16 * it;                 // 0..31
            const int k0 = 16 * kg + 4 * quad;
            f32x4 vr[4];
            #pragma unroll
            for (int kk = 0; kk < 4; ++kk) {
                int krow = LB + k0 + kk; krow = krow < SEQ ? krow : SEQ - 1;
                vr[kk] = *reinterpret_cast<const f32x4*>(Vp + (size_t)krow * DIM + 4 * colq);
            }
            #pragma unroll
            for (int i = 0; i < 4; ++i) {
                const int d  = 4 * colq + i;
                const int gd = (d ^ (d >> 2)) & 7;
                u32x2 o;
                o[0] = pk2(vr[0][i], vr[1][i]);
                o[1] = pk2(vr[2][i], vr[3][i]);
                *reinterpret_cast<u32x2*>(&Vt[d][k0 ^ (8 * gd)]) = o;
            }
        }
    }
    __syncthreads();   // the ONLY barrier — all waves fully independent after this

    float m = -3.0e38f, S0 = 0.f, S1 = 0.f;
    f32x4 accX[4], accY[4];
    #pragma unroll
    for (int dt = 0; dt < 4; ++dt) {
        accX[dt][0]=0.f; accX[dt][1]=0.f; accX[dt][2]=0.f; accX[dt][3]=0.f;
        accY[dt][0]=0.f; accY[dt][1]=0.f; accY[dt][2]=0.f; accY[dt][3]=0.f;
    }

    const float* Mq = M + (size_t)b * SEQ + kb0;   // mask, always in-bounds
    const int kswz = 8 * (lo & 7);
    const int pswz = 4 * (lo & 7);

    #pragma unroll
    for (int ps = 0; ps < 2; ++ps) {
        const int kb = off + 192 * ps;   // LDS-local key base of this pass

        // ---- QK^T swapped: st[l] -> S[key=16l+4hi+r][q=lo] ----
        f32x4 st[12];
        #pragma unroll
        for (int l = 0; l < 12; ++l) { st[l][0]=0.f; st[l][1]=0.f; st[l][2]=0.f; st[l][3]=0.f; }
        __builtin_amdgcn_s_setprio(1);
        #pragma unroll
        for (int s = 0; s < 2; ++s)
            #pragma unroll
            for (int l = 0; l < 12; ++l) {
                short8 kf = *reinterpret_cast<const short8*>(
                    &Ks[kb + 16 * l + lo][(32 * s + 8 * hi) ^ kswz]);
                st[l] = __builtin_amdgcn_mfma_f32_16x16x32_bf16(kf, qa[s], st[l], 0, 0, 0);
            }
        __builtin_amdgcn_s_setprio(0);

        // ---- mask (global, L2-resident; pre-scale by log2e) ----
        #pragma unroll
        for (int l = 0; l < 12; ++l) {
            f32x4 mv = *reinterpret_cast<const f32x4*>(Mq + 192 * ps + 16 * l + 4 * hi);
            #pragma unroll
            for (int r = 0; r < 4; ++r) st[l][r] = fmaf(mv[r], LOG2E, st[l][r]);
        }

        // ---- online softmax (q = lo; row max via xor16/32) ----
        float mx = st[0][0];
        #pragma unroll
        for (int l = 0; l < 12; ++l)
            #pragma unroll
            for (int r = 0; r < 4; ++r) mx = fmaxf(mx, st[l][r]);
        mx = fmaxf(mx, __shfl_xor(mx, 16));
        mx = fmaxf(mx, __shfl_xor(mx, 32));
        const float mn = fmaxf(m, mx);
        if (ps) {
            const float f = exp2f(m - mn);   // lane-local: acc is O^T layout (q = lo)
            S0 *= f; S1 *= f;
            #pragma unroll
            for (int dt = 0; dt < 4; ++dt)
                #pragma unroll
                for (int r = 0; r < 4; ++r) { accX[dt][r] *= f; accY[dt][r] *= f; }
        }
        m = mn;

        #pragma unroll
        for (int l = 0; l < 12; ++l)
            #pragma unroll
            for (int r = 0; r < 4; ++r) st[l][r] = exp2f(st[l][r] - m);

        // window sums (lane-partial; reduced once at the end):
        // W0 = span tiles 0..15, W1 = tiles 8..23 (tile T = 12*ps + l)
        float s0l = 0.f, s1l = 0.f;
        #pragma unroll
        for (int l = 0; l < 12; ++l) {
            const float t = (st[l][0] + st[l][1]) + (st[l][2] + st[l][3]);
            if (ps == 0) { s0l += t; if (l >= 8) s1l += t; }
            else         { s1l += t; if (l < 4)  s0l += t; }
        }
        S0 += s0l; S1 += s1l;

        // ---- pack P (unweighted) ----
        unsigned int pk[24];
        #pragma unroll
        for (int l = 0; l < 12; ++l) {
            pk[2 * l]     = pk2(st[l][0], st[l][1]);
            pk[2 * l + 1] = pk2(st[l][2], st[l][3]);
        }

        // ---- PV swapped (O^T): overlap tiles feed both accumulators ----
        #pragma unroll
        for (int kq = 0; kq < 6; ++kq) {
            const int pp = 16 * (kq & 1);
            u32x2 w0v, w1v;
            w0v[0] = pk[4 * kq + 0]; w0v[1] = pk[4 * kq + 1];
            w1v[0] = pk[4 * kq + 2]; w1v[1] = pk[4 * kq + 3];
            *reinterpret_cast<u32x2*>(&Pw[w][lo][(pp + 2 * hi)     ^ pswz]) = w0v;
            *reinterpret_cast<u32x2*>(&Pw[w][lo][(pp + 8 + 2 * hi) ^ pswz]) = w1v;
            short8 pf = *reinterpret_cast<const short8*>(&Pw[w][lo][(pp + 4 * hi) ^ pswz]);
            const bool toX = (ps == 0) ? true : (kq < 2);
            const bool toY = (ps == 0) ? (kq >= 4) : true;
            __builtin_amdgcn_s_setprio(1);
            #pragma unroll
            for (int dt = 0; dt < 4; ++dt) {
                const int d  = 16 * dt + lo;
                const int gd = (d ^ (d >> 2)) & 7;
                short8 vf = *reinterpret_cast<const short8*>(
                    &Vt[d][(kb + 32 * kq + 8 * hi) ^ (8 * gd)]);
                if (toX) accX[dt] = __builtin_amdgcn_mfma_f32_16x16x32_bf16(vf, pf, accX[dt], 0, 0, 0);
                if (toY) accY[dt] = __builtin_amdgcn_mfma_f32_16x16x32_bf16(vf, pf, accY[dt], 0, 0, 0);
            }
            __builtin_amdgcn_s_setprio(0);
        }
    }

    // ---- finalize: everything lane-local in q = lo ----
    S0 += __shfl_xor(S0, 16); S0 += __shfl_xor(S0, 32);
    S1 += __shfl_xor(S1, 16); S1 += __shfl_xor(S1, 32);
    const float b0 = wt0 / S0;
    const float b1 = wt1 / S1;
    float* Opr = O + base + (size_t)(q0 + lo) * DIM + 4 * hi;
    #pragma unroll
    for (int dt = 0; dt < 4; ++dt) {
        f32x4 o;
        #pragma unroll
        for (int r = 0; r < 4; ++r) o[r] = b0 * accX[dt][r] + b1 * accY[dt][r];
        *reinterpret_cast<f32x4*>(Opr + 16 * dt) = o;   // O[q0+lo][16dt+4hi .. +4]
    }
}

extern "C" void kernel_launch(void* const* d_in, const int* in_sizes, int n_in,
                              void* d_out, int out_size, void* d_ws, size_t ws_size,
                              hipStream_t stream) {
    const float* Q = (const float*)d_in[0];
    const float* K = (const float*)d_in[1];
    const float* V = (const float*)d_in[2];
    const float* M = (const float*)d_in[3];
    float* O = (float*)d_out;
    blk_attn<<<dim3(NB * NH * (SEQ / 256)), dim3(1024), 0, stream>>>(Q, K, V, M, O);
}

// Round 10
// 86.360 us; speedup vs baseline: 1.8195x; 1.8195x over previous
//
#include <hip/hip_runtime.h>
#include <hip/hip_bf16.h>

#define NB 4
#define NH 12
#define SEQ 4096
#define DIM 64
#define LOG2E 1.4426950408889634f

typedef __attribute__((ext_vector_type(8))) short short8;
typedef __attribute__((ext_vector_type(4))) float f32x4;
typedef __attribute__((ext_vector_type(2))) unsigned int u32x2;

static __device__ __forceinline__ unsigned int pk2(float a, float b) {
    float2 t; t.x = a; t.y = b;
    union { __hip_bfloat162 h; unsigned int u; } x;
    x.h = __float22bfloat162_rn(t);
    return x.u;
}
static __device__ __forceinline__ short8 mk8(unsigned int a, unsigned int b,
                                             unsigned int c, unsigned int d) {
    union { unsigned int u[4]; short8 s; } x;
    x.u[0] = a; x.u[1] = b; x.u[2] = c; x.u[3] = d;
    return x.s;
}

__global__ __launch_bounds__(512, 2)
void blk_attn(const float* __restrict__ Q, const float* __restrict__ K,
              const float* __restrict__ V, const float* __restrict__ M,
              float* __restrict__ O) {
    int bid = blockIdx.x;
    bid = (bid & 7) * 192 + (bid >> 3);   // XCD-aware bijective swizzle (1536 % 8 == 0)

    const int j  = bid & 31;   // 128-query group; key stride 128 -> L2 set 2.2MB/XCD
    const int bh = bid >> 5;
    const int b  = bh / NH;

    const size_t base = (size_t)bh * SEQ * DIM;
    const float* Kp = K + base;
    const float* Vp = V + base;

    const int tid  = threadIdx.x;
    const int w    = tid >> 6;      // wave 0..7, owns queries [16w, 16w+16)
    const int lane = tid & 63;
    const int lo   = lane & 15;
    const int hi   = lane >> 4;

    // span [kb0, kb0+384): W0 = tiles 0..15, W1 = tiles 8..23 (always in-bounds)
    const int  kb0 = (j == 0) ? 0 : ((j == 31) ? SEQ - 384 : 128 * j - 128);
    const bool md  = (j != 0) && (j != 31);
    const float wt0 = (j == 31) ? 0.f : (md ? 0.5f : 1.f);
    const float wt1 = (j == 0)  ? 0.f : (md ? 0.5f : 1.f);

    // ---- LDS: 112 KB ----
    __shared__ __align__(16) unsigned char smem[114688];
    auto Ks = (unsigned short (*)[64])(smem);            // [384][64]: K[key][d ^ 8*(key&7)]
    auto Vt = (unsigned short (*)[384])(smem + 49152);   // [64][384]: V^T[d][k ^ 8*((d^(d>>2))&7)]
    auto Pw = (unsigned int (*)[16][32])(smem + 98304);  // [8 waves][16 q][32 dw]

    // ---- Q fragments, scaled by log2e/8 ----
    short8 qa[2];
    {
        const float qs = 0.125f * LOG2E;
        const float* qr = Q + base + (size_t)(128 * j + 16 * w + lo) * DIM + hi * 8;
        #pragma unroll
        for (int s = 0; s < 2; ++s) {
            f32x4 a = *reinterpret_cast<const f32x4*>(qr + 32 * s);
            f32x4 c = *reinterpret_cast<const f32x4*>(qr + 32 * s + 4);
            qa[s] = mk8(pk2(a[0] * qs, a[1] * qs), pk2(a[2] * qs, a[3] * qs),
                        pk2(c[0] * qs, c[1] * qs), pk2(c[2] * qs, c[3] * qs));
        }
    }

    // ---- stage K: 384 rows, b128 conflict-free writes ----
    {
        const int c8 = lane & 7, r8 = lane >> 3;
        #pragma unroll
        for (int it = 0; it < 6; ++it) {
            const int row = 8 * w + r8 + 64 * it;        // row & 7 == r8
            const float* kp = Kp + (size_t)(kb0 + row) * DIM + 8 * c8;
            f32x4 a = *reinterpret_cast<const f32x4*>(kp);
            f32x4 c = *reinterpret_cast<const f32x4*>(kp + 4);
            *reinterpret_cast<short8*>(&Ks[row][(8 * c8) ^ (8 * r8)]) =
                mk8(pk2(a[0], a[1]), pk2(a[2], a[3]), pk2(c[0], c[1]), pk2(c[2], c[3]));
        }
    }
    // ---- stage V^T: 4x4 register transpose, b64 conflict-light writes ----
    {
        const int quad = lane & 3, colq = lane >> 2;
        #pragma unroll
        for (int it = 0; it < 3; ++it) {
            const int kg = w + 8 * it;                   // 0..23
            const int k0 = 16 * kg + 4 * quad;
            f32x4 vr[4];
            #pragma unroll
            for (int kk = 0; kk < 4; ++kk)
                vr[kk] = *reinterpret_cast<const f32x4*>(
                    Vp + (size_t)(kb0 + k0 + kk) * DIM + 4 * colq);
            #pragma unroll
            for (int i = 0; i < 4; ++i) {
                const int d  = 4 * colq + i;
                const int gd = (d ^ (d >> 2)) & 7;
                u32x2 o;
                o[0] = pk2(vr[0][i], vr[1][i]);
                o[1] = pk2(vr[2][i], vr[3][i]);
                *reinterpret_cast<u32x2*>(&Vt[d][k0 ^ (8 * gd)]) = o;
            }
        }
    }
    __syncthreads();   // the ONLY barrier — waves fully independent after this

    float m = -3.0e38f, S0 = 0.f, S1 = 0.f;
    f32x4 accX[4], accY[4];
    #pragma unroll
    for (int dt = 0; dt < 4; ++dt) {
        accX[dt][0]=0.f; accX[dt][1]=0.f; accX[dt][2]=0.f; accX[dt][3]=0.f;
        accY[dt][0]=0.f; accY[dt][1]=0.f; accY[dt][2]=0.f; accY[dt][3]=0.f;
    }

    const float* Mq = M + (size_t)b * SEQ + kb0;
    const int kswz = 8 * (lo & 7);
    const int pswz = 4 * (lo & 7);

    #pragma unroll
    for (int ps = 0; ps < 2; ++ps) {
        const int kb = 192 * ps;

        // ---- QK^T swapped: st[l] -> S[key=16l+4hi+r][q=lo] ----
        f32x4 st[12];
        #pragma unroll
        for (int l = 0; l < 12; ++l) { st[l][0]=0.f; st[l][1]=0.f; st[l][2]=0.f; st[l][3]=0.f; }
        __builtin_amdgcn_s_setprio(1);
        #pragma unroll
        for (int s = 0; s < 2; ++s)
            #pragma unroll
            for (int l = 0; l < 12; ++l) {
                short8 kf = *reinterpret_cast<const short8*>(
                    &Ks[kb + 16 * l + lo][(32 * s + 8 * hi) ^ kswz]);
                st[l] = __builtin_amdgcn_mfma_f32_16x16x32_bf16(kf, qa[s], st[l], 0, 0, 0);
            }
        __builtin_amdgcn_s_setprio(0);

        // ---- mask (global, L2-resident; pre-scaled by log2e) ----
        #pragma unroll
        for (int l = 0; l < 12; ++l) {
            f32x4 mv = *reinterpret_cast<const f32x4*>(Mq + kb + 16 * l + 4 * hi);
            #pragma unroll
            for (int r = 0; r < 4; ++r) st[l][r] = fmaf(mv[r], LOG2E, st[l][r]);
        }

        // ---- online softmax (q = lo; row max via xor16/32) ----
        float mx = st[0][0];
        #pragma unroll
        for (int l = 0; l < 12; ++l)
            #pragma unroll
            for (int r = 0; r < 4; ++r) mx = fmaxf(mx, st[l][r]);
        mx = fmaxf(mx, __shfl_xor(mx, 16));
        mx = fmaxf(mx, __shfl_xor(mx, 32));
        const float mn = fmaxf(m, mx);
        if (ps) {
            const float f = exp2f(m - mn);   // lane-local: acc is O^T layout (q = lo)
            S0 *= f; S1 *= f;
            #pragma unroll
            for (int dt = 0; dt < 4; ++dt)
                #pragma unroll
                for (int r = 0; r < 4; ++r) { accX[dt][r] *= f; accY[dt][r] *= f; }
        }
        m = mn;

        #pragma unroll
        for (int l = 0; l < 12; ++l)
            #pragma unroll
            for (int r = 0; r < 4; ++r) st[l][r] = exp2f(st[l][r] - m);

        // window sums: W0 = span tiles 0..15, W1 = tiles 8..23 (tile = 12*ps + l)
        float s0l = 0.f, s1l = 0.f;
        #pragma unroll
        for (int l = 0; l < 12; ++l) {
            const float t = (st[l][0] + st[l][1]) + (st[l][2] + st[l][3]);
            if (ps == 0) { s0l += t; if (l >= 8) s1l += t; }
            else         { s1l += t; if (l < 4)  s0l += t; }
        }
        S0 += s0l; S1 += s1l;

        // ---- pack P (unweighted) ----
        unsigned int pk[24];
        #pragma unroll
        for (int l = 0; l < 12; ++l) {
            pk[2 * l]     = pk2(st[l][0], st[l][1]);
            pk[2 * l + 1] = pk2(st[l][2], st[l][3]);
        }

        // ---- PV swapped (O^T): overlap tiles feed both accumulators ----
        #pragma unroll
        for (int kq = 0; kq < 6; ++kq) {
            const int pp = 16 * (kq & 1);
            u32x2 w0v, w1v;
            w0v[0] = pk[4 * kq + 0]; w0v[1] = pk[4 * kq + 1];
            w1v[0] = pk[4 * kq + 2]; w1v[1] = pk[4 * kq + 3];
            *reinterpret_cast<u32x2*>(&Pw[w][lo][(pp + 2 * hi)     ^ pswz]) = w0v;
            *reinterpret_cast<u32x2*>(&Pw[w][lo][(pp + 8 + 2 * hi) ^ pswz]) = w1v;
            short8 pf = *reinterpret_cast<const short8*>(&Pw[w][lo][(pp + 4 * hi) ^ pswz]);
            const bool toX = (ps == 0) ? true : (kq < 2);
            const bool toY = (ps == 0) ? (kq >= 4) : true;
            __builtin_amdgcn_s_setprio(1);
            #pragma unroll
            for (int dt = 0; dt < 4; ++dt) {
                const int d  = 16 * dt + lo;
                const int gd = (d ^ (d >> 2)) & 7;
                short8 vf = *reinterpret_cast<const short8*>(
                    &Vt[d][(kb + 32 * kq + 8 * hi) ^ (8 * gd)]);
                if (toX) accX[dt] = __builtin_amdgcn_mfma_f32_16x16x32_bf16(vf, pf, accX[dt], 0, 0, 0);
                if (toY) accY[dt] = __builtin_amdgcn_mfma_f32_16x16x32_bf16(vf, pf, accY[dt], 0, 0, 0);
            }
            __builtin_amdgcn_s_setprio(0);
        }
    }

    // ---- finalize: lane-local (q = lo), contiguous f32x4 store ----
    S0 += __shfl_xor(S0, 16); S0 += __shfl_xor(S0, 32);
    S1 += __shfl_xor(S1, 16); S1 += __shfl_xor(S1, 32);
    const float b0 = wt0 / S0;
    const float b1 = wt1 / S1;
    float* Opr = O + base + (size_t)(128 * j + 16 * w + lo) * DIM + 4 * hi;
    #pragma unroll
    for (int dt = 0; dt < 4; ++dt) {
        f32x4 o;
        #pragma unroll
        for (int r = 0; r < 4; ++r) o[r] = b0 * accX[dt][r] + b1 * accY[dt][r];
        *reinterpret_cast<f32x4*>(Opr + 16 * dt) = o;
    }
}

extern "C" void kernel_launch(void* const* d_in, const int* in_sizes, int n_in,
                              void* d_out, int out_size, void* d_ws, size_t ws_size,
                              hipStream_t stream) {
    const float* Q = (const float*)d_in[0];
    const float* K = (const float*)d_in[1];
    const float* V = (const float*)d_in[2];
    const float* M = (const float*)d_in[3];
    float* O = (float*)d_out;
    blk_attn<<<dim3(NB * NH * (SEQ / 128)), dim3(512), 0, stream>>>(Q, K, V, M, O);
}